// Round 1
// baseline (665.053 us; speedup 1.0000x reference)
//
#include <hip/hip_runtime.h>
#include <cstddef>

namespace nl {
constexpr int B = 2, C = 3, H = 63, W = 63, K = 7;
constexpr int NH = 57, NW = 57, N = NH * NW;      // 3249
constexpr int KS = 147, KSP = 160, NPAD = 3328;   // padded dims for clean tiling
constexpr size_t SZ_X   = (size_t)B * KSP * NPAD; // 1,064,960 floats
constexpr size_t OFF_XR = 0;                      // ref patches (from y)
constexpr size_t OFF_XI = OFF_XR + SZ_X;          // inp patches (from x)
constexpr size_t OFF_SQ = OFF_XI + SZ_X;          // [B][NPAD]
constexpr size_t OFF_HD = OFF_SQ + (size_t)B * NPAD;   // h*h+1
constexpr size_t OFF_BLK = OFF_HD + (size_t)B * NPAD;  // blk_p
constexpr size_t OFF_D  = OFF_BLK + (size_t)B * NPAD;  // softmax denominators
constexpr size_t OFF_BIMG = OFF_D + (size_t)B * NPAD;  // block image, B*63*63 -> 8192
constexpr size_t OFF_ATT = OFF_BIMG + 8192;
constexpr size_t SZ_ATT = (size_t)B * NPAD * NPAD;     // 22,151,168 floats
constexpr size_t OFF_OUTA = OFF_ATT + SZ_ATT;          // split-K partial 0
constexpr size_t OFF_OUTB = OFF_OUTA + SZ_X;           // split-K partial 1
// total = OFF_OUTB + SZ_X = 26,445,824 floats = ~101 MiB
}
using namespace nl;

// ---------------- block detect (sobel + angle test) ----------------
__global__ __launch_bounds__(256) void nl_block(const float* __restrict__ x,
                                                const float* __restrict__ y,
                                                float* __restrict__ bimg) {
  int idx = blockIdx.x * 256 + threadIdx.x;
  if (idx >= B * H * W) return;
  int q = idx % W, t = idx / W;
  int p = t % H, b = t / H;
  float gx[3][3], gy[3][3];
#pragma unroll
  for (int dy = 0; dy < 3; ++dy)
#pragma unroll
    for (int dx = 0; dx < 3; ++dx) {
      int pp = p + dy - 1, qq = q + dx - 1;
      float vx = 0.f, vy = 0.f;
      if (pp >= 0 && pp < H && qq >= 0 && qq < W) {
        int base = (b * C * H + pp) * W + qq;
        vx = 0.299f * x[base] + 0.587f * x[base + H * W] + 0.114f * x[base + 2 * H * W];
        vy = 0.299f * y[base] + 0.587f * y[base + H * W] + 0.114f * y[base + 2 * H * W];
      }
      gx[dy][dx] = vx; gy[dy][dx] = vy;
    }
  float in_gx = (q == W - 1) ? 1.f : (-gx[0][0] + gx[0][2] - 2.f * gx[1][0] + 2.f * gx[1][2] - gx[2][0] + gx[2][2]);
  float in_gy = (p == H - 1) ? 1.f : (-gx[0][0] - 2.f * gx[0][1] - gx[0][2] + gx[2][0] + 2.f * gx[2][1] + gx[2][2]);
  float rf_gx = (q == W - 1) ? 1.f : (-gy[0][0] + gy[0][2] - 2.f * gy[1][0] + 2.f * gy[1][2] - gy[2][0] + gy[2][2]);
  float rf_gy = (p == H - 1) ? 1.f : (-gy[0][0] - 2.f * gy[0][1] - gy[0][2] + gy[2][0] + 2.f * gy[2][1] + gy[2][2]);
  float n_in = sqrtf(in_gx * in_gx + in_gy * in_gy);
  float n_rf = sqrtf(rf_gx * rf_gx + rf_gy * rf_gy);
  float cosv = (in_gx * rf_gx + in_gy * rf_gy + 0.001f) / (n_in * n_rf + 0.001f);
  float det = (n_in >= 29.f) ? ((n_rf >= 29.f) ? (1.f - cosv) : 1.f) : 0.f;
  bimg[(b * H + p) * W + q] = 1.f - det;
}

// ---------------- blk_p: 7x7 box mean of block image ----------------
__global__ __launch_bounds__(256) void nl_blkp(const float* __restrict__ bimg,
                                               float* __restrict__ blk) {
  int idx = blockIdx.x * 256 + threadIdx.x;
  if (idx >= B * NPAD) return;
  int n = idx % NPAD, b = idx / NPAD;
  float v = 0.f;
  if (n < N) {
    int i = n / NW, j = n % NW;
    float s = 0.f;
#pragma unroll
    for (int ky = 0; ky < K; ++ky)
#pragma unroll
      for (int kx = 0; kx < K; ++kx)
        s += bimg[(b * H + i + ky) * W + (j + kx)];
    v = s * (1.f / 49.f);
  }
  blk[idx] = v;
}

// ---------------- im2col for both images (zero-padded to [KSP][NPAD]) ----------------
__global__ __launch_bounds__(256) void nl_im2col(const float* __restrict__ x,
                                                 const float* __restrict__ y,
                                                 float* __restrict__ ws) {
  int idx = blockIdx.x * 256 + threadIdx.x;
  if (idx >= (int)(2 * SZ_X)) return;
  int n = idx % NPAD;
  int r1 = idx / NPAD;
  int k = r1 % KSP;
  int r2 = r1 / KSP;
  int b = r2 % B;
  int which = r2 / B;  // 0 -> Xr (from y), 1 -> Xi (from x)
  float v = 0.f;
  if (k < KS && n < N) {
    int c = k / 49, r = k % 49;
    int ky = r / 7, kx = r % 7;
    int i = n / NW, j = n % NW;
    const float* src = which ? x : y;
    v = src[((b * C + c) * H + (i + ky)) * W + (j + kx)];
  }
  ws[OFF_XR + idx] = v;
}

// ---------------- per-query sq = |patch|^2 and h-network ----------------
__global__ __launch_bounds__(256) void nl_sqh(const float* __restrict__ ws_xr,
                                              const float* __restrict__ w1,
                                              const float* __restrict__ b1,
                                              const float* __restrict__ w2,
                                              const float* __restrict__ b2,
                                              float* __restrict__ sq,
                                              float* __restrict__ hd) {
  int idx = blockIdx.x * 256 + threadIdx.x;
  if (idx >= B * NPAD) return;
  int n = idx % NPAD, b = idx / NPAD;
  if (n >= N) { sq[idx] = 0.f; hd[idx] = 1.f; return; }
  const float* Xr = ws_xr + (size_t)b * KSP * NPAD + n;
  float s = 0.f, h0 = b1[0], h1 = b1[1], h2 = b1[2];
  for (int k = 0; k < KS; ++k) {
    float v = Xr[(size_t)k * NPAD];
    s += v * v;
    h0 += v * w1[k];
    h1 += v * w1[KS + k];
    h2 += v * w1[2 * KS + k];
  }
  h0 = fmaxf(h0, 0.f); h1 = fmaxf(h1, 0.f); h2 = fmaxf(h2, 0.f);
  float h = h0 * w2[0] + h1 * w2[1] + h2 * w2[2] + b2[0];
  sq[idx] = s;
  hd[idx] = h * h + 1.f;
}

// ---------------- GEMM1: att = (2*Xr^T Xr - sq_n - sq_m) / hd_n ----------------
__global__ __launch_bounds__(256) void nl_gemm1(const float* __restrict__ ws_xr,
                                                const float* __restrict__ sq,
                                                const float* __restrict__ hd,
                                                float* __restrict__ att) {
  __shared__ float As[32][128];
  __shared__ float Bs[32][128];
  int b = blockIdx.z;
  const float* Xb = ws_xr + (size_t)b * KSP * NPAD;
  int row0 = blockIdx.y * 128, col0 = blockIdx.x * 128;
  int t = threadIdx.x;
  int tr = t >> 4, tc = t & 15;
  float acc[8][8];
#pragma unroll
  for (int i = 0; i < 8; ++i)
#pragma unroll
    for (int j = 0; j < 8; ++j) acc[i][j] = 0.f;

  for (int kt = 0; kt < KSP; kt += 32) {
#pragma unroll
    for (int u = 0; u < 4; ++u) {
      int e = t + u * 256;        // float4 id 0..1023
      int kk = e >> 5, cc = e & 31;
      float4 va = *(const float4*)(Xb + (size_t)(kt + kk) * NPAD + row0 + cc * 4);
      *(float4*)(&As[kk][cc * 4]) = va;
      float4 vb = *(const float4*)(Xb + (size_t)(kt + kk) * NPAD + col0 + cc * 4);
      *(float4*)(&Bs[kk][cc * 4]) = vb;
    }
    __syncthreads();
#pragma unroll
    for (int kk = 0; kk < 32; ++kk) {
      float a[8], bb[8];
      *(float4*)(&a[0]) = *(const float4*)(&As[kk][tr * 8]);
      *(float4*)(&a[4]) = *(const float4*)(&As[kk][tr * 8 + 4]);
      *(float4*)(&bb[0]) = *(const float4*)(&Bs[kk][tc * 8]);
      *(float4*)(&bb[4]) = *(const float4*)(&Bs[kk][tc * 8 + 4]);
#pragma unroll
      for (int i = 0; i < 8; ++i)
#pragma unroll
        for (int j = 0; j < 8; ++j) acc[i][j] = fmaf(a[i], bb[j], acc[i][j]);
    }
    __syncthreads();
  }
  float sqn[8], hdn[8], sqm[8];
#pragma unroll
  for (int i = 0; i < 8; ++i) {
    sqn[i] = sq[b * NPAD + row0 + tr * 8 + i];
    hdn[i] = hd[b * NPAD + row0 + tr * 8 + i];
  }
#pragma unroll
  for (int j = 0; j < 8; ++j) sqm[j] = sq[b * NPAD + col0 + tc * 8 + j];
  float* arow = att + ((size_t)b * NPAD + row0 + tr * 8) * NPAD + col0 + tc * 8;
#pragma unroll
  for (int i = 0; i < 8; ++i) {
    float v[8];
#pragma unroll
    for (int j = 0; j < 8; ++j)
      v[j] = (2.f * acc[i][j] - sqn[i] - sqm[j]) / hdn[i];
    *(float4*)(arow + (size_t)i * NPAD) = *(float4*)(&v[0]);
    *(float4*)(arow + (size_t)i * NPAD + 4) = *(float4*)(&v[4]);
  }
}

// ---------------- softmax rows: store e*blk, denominators to D ----------------
__global__ __launch_bounds__(256) void nl_softmax(float* __restrict__ att,
                                                  const float* __restrict__ blk,
                                                  float* __restrict__ Dv) {
  int n = blockIdx.x, b = blockIdx.y;
  int tid = threadIdx.x;
  float* row = att + ((size_t)b * NPAD + n) * NPAD;
  __shared__ float red[256];
  float lmax = -1e30f;
  for (int m = tid; m < N; m += 256) lmax = fmaxf(lmax, row[m]);
  red[tid] = lmax;
  __syncthreads();
  for (int s = 128; s > 0; s >>= 1) {
    if (tid < s) red[tid] = fmaxf(red[tid], red[tid + s]);
    __syncthreads();
  }
  float mx = red[0];
  __syncthreads();
  const float* bl = blk + b * NPAD;
  float s1 = 0.f, s2 = 0.f;
  for (int m = tid; m < N; m += 256) {
    float e = __expf(row[m] - mx);
    float eb = e * bl[m];
    row[m] = eb;
    s1 += e;
    s2 += eb;
  }
  for (int m = N + tid; m < NPAD; m += 256) row[m] = 0.f;  // zero pad cols
  red[tid] = s1;
  __syncthreads();
  for (int s = 128; s > 0; s >>= 1) {
    if (tid < s) red[tid] += red[tid + s];
    __syncthreads();
  }
  float s1t = red[0];
  __syncthreads();
  red[tid] = s2;
  __syncthreads();
  for (int s = 128; s > 0; s >>= 1) {
    if (tid < s) red[tid] += red[tid + s];
    __syncthreads();
  }
  if (tid == 0) Dv[b * NPAD + n] = red[0] + 0.001f * s1t;
}

// ---------------- GEMM2: out_p[k,n] = sum_m att[n,m]*Xi[k,m] / D[n], split-K=2 ----------------
__global__ __launch_bounds__(256) void nl_gemm2(const float* __restrict__ att,
                                                const float* __restrict__ ws_xi,
                                                const float* __restrict__ Dv,
                                                float* __restrict__ outA,
                                                float* __restrict__ outB) {
  __shared__ float Ps[32][65];    // [m][n] transposed in LDS
  __shared__ float Xs[32][161];   // [m][k]
  int b = blockIdx.z;
  int n0 = blockIdx.x * 64;
  int m0 = blockIdx.y * (NPAD / 2);  // 1664 per split
  const float* attb = att + (size_t)b * NPAD * NPAD;
  const float* Xib = ws_xi + (size_t)b * KSP * NPAD;
  int t = threadIdx.x;
  int tn8 = t & 7;        // n = tn8 + 8*i
  int tk32 = t >> 3;      // k = tk32*5 + j
  float acc[8][5];
#pragma unroll
  for (int i = 0; i < 8; ++i)
#pragma unroll
    for (int j = 0; j < 5; ++j) acc[i][j] = 0.f;

  for (int mt = m0; mt < m0 + NPAD / 2; mt += 32) {
#pragma unroll
    for (int u = 0; u < 2; ++u) {  // att tile 64x32
      int e = t + u * 256;
      int r = e >> 3, c4 = e & 7;
      float4 v = *(const float4*)(attb + (size_t)(n0 + r) * NPAD + mt + c4 * 4);
      Ps[c4 * 4 + 0][r] = v.x; Ps[c4 * 4 + 1][r] = v.y;
      Ps[c4 * 4 + 2][r] = v.z; Ps[c4 * 4 + 3][r] = v.w;
    }
#pragma unroll
    for (int u = 0; u < 5; ++u) {  // Xi tile 160x32
      int e = t + u * 256;
      int r = e >> 3, c4 = e & 7;
      float4 v = *(const float4*)(Xib + (size_t)r * NPAD + mt + c4 * 4);
      Xs[c4 * 4 + 0][r] = v.x; Xs[c4 * 4 + 1][r] = v.y;
      Xs[c4 * 4 + 2][r] = v.z; Xs[c4 * 4 + 3][r] = v.w;
    }
    __syncthreads();
#pragma unroll
    for (int mm = 0; mm < 32; ++mm) {
      float a[8], bb[5];
#pragma unroll
      for (int i = 0; i < 8; ++i) a[i] = Ps[mm][tn8 + 8 * i];
#pragma unroll
      for (int j = 0; j < 5; ++j) bb[j] = Xs[mm][tk32 * 5 + j];
#pragma unroll
      for (int i = 0; i < 8; ++i)
#pragma unroll
        for (int j = 0; j < 5; ++j) acc[i][j] = fmaf(a[i], bb[j], acc[i][j]);
    }
    __syncthreads();
  }
  float* outp = (blockIdx.y ? outB : outA) + (size_t)b * KSP * NPAD;
#pragma unroll
  for (int i = 0; i < 8; ++i) {
    int n = n0 + tn8 + 8 * i;
    if (n < N) {
      float d = Dv[b * NPAD + n];
#pragma unroll
      for (int j = 0; j < 5; ++j) {
        int k = tk32 * 5 + j;
        outp[(size_t)k * NPAD + n] = acc[i][j] / d;
      }
    }
  }
}

// ---------------- fold (overlap-add adjoint of im2col) + weight divide ----------------
__global__ __launch_bounds__(256) void nl_fold(const float* __restrict__ outA,
                                               const float* __restrict__ outB,
                                               float* __restrict__ out) {
  int idx = blockIdx.x * 256 + threadIdx.x;
  if (idx >= B * C * H * W) return;
  int q = idx % W, t = idx / W;
  int p = t % H, t2 = t / H;
  int c = t2 % C, b = t2 / C;
  float s = 0.f;
#pragma unroll
  for (int ky = 0; ky < K; ++ky) {
    int iy = p - ky;
    if (iy < 0 || iy >= NH) continue;
#pragma unroll
    for (int kx = 0; kx < K; ++kx) {
      int jx = q - kx;
      if (jx < 0 || jx >= NW) continue;
      size_t o = ((size_t)(b * KSP + c * 49 + ky * 7 + kx)) * NPAD + iy * NW + jx;
      s += outA[o] + outB[o];
    }
  }
  int cy = min(p, 6) - max(0, p - 56) + 1;
  int cx = min(q, 6) - max(0, q - 56) + 1;
  out[idx] = s / (float)(cy * cx);
}

extern "C" void kernel_launch(void* const* d_in, const int* in_sizes, int n_in,
                              void* d_out, int out_size, void* d_ws, size_t ws_size,
                              hipStream_t stream) {
  const float* x = (const float*)d_in[0];
  const float* y = (const float*)d_in[1];
  const float* w1 = (const float*)d_in[2];
  const float* b1 = (const float*)d_in[3];
  const float* w2 = (const float*)d_in[4];
  const float* b2 = (const float*)d_in[5];
  float* ws = (float*)d_ws;
  float* out = (float*)d_out;

  float* Xr = ws + OFF_XR;
  float* Xi = ws + OFF_XI;
  float* sq = ws + OFF_SQ;
  float* hd = ws + OFF_HD;
  float* blk = ws + OFF_BLK;
  float* Dv = ws + OFF_D;
  float* bimg = ws + OFF_BIMG;
  float* att = ws + OFF_ATT;
  float* outA = ws + OFF_OUTA;
  float* outB = ws + OFF_OUTB;

  nl_block<<<(B * H * W + 255) / 256, 256, 0, stream>>>(x, y, bimg);
  nl_im2col<<<(int)((2 * SZ_X + 255) / 256), 256, 0, stream>>>(x, y, ws);
  nl_blkp<<<(B * NPAD + 255) / 256, 256, 0, stream>>>(bimg, blk);
  nl_sqh<<<(B * NPAD + 255) / 256, 256, 0, stream>>>(Xr, w1, b1, w2, b2, sq, hd);
  nl_gemm1<<<dim3(NPAD / 128, NPAD / 128, B), 256, 0, stream>>>(Xr, sq, hd, att);
  nl_softmax<<<dim3(N, B), 256, 0, stream>>>(att, blk, Dv);
  nl_gemm2<<<dim3(NPAD / 64, 2, B), 256, 0, stream>>>(att, Xi, Dv, outA, outB);
  nl_fold<<<(B * C * H * W + 255) / 256, 256, 0, stream>>>(outA, outB, out);
}

// Round 2
// 499.786 us; speedup vs baseline: 1.3307x; 1.3307x over previous
//
#include <hip/hip_runtime.h>
#include <cstddef>

namespace nl {
constexpr int B = 2, C = 3, H = 63, W = 63, K = 7;
constexpr int NH = 57, NW = 57, N = NH * NW;      // 3249
constexpr int KS = 147, KSP = 160, NPAD = 3328;   // padded dims for clean tiling
constexpr size_t SZ_X   = (size_t)B * KSP * NPAD; // 1,064,960 floats
constexpr size_t OFF_XR = 0;                      // ref patches (from y)
constexpr size_t OFF_XI = OFF_XR + SZ_X;          // inp patches (from x)
constexpr size_t OFF_SQ = OFF_XI + SZ_X;          // [B][NPAD]
constexpr size_t OFF_HD = OFF_SQ + (size_t)B * NPAD;   // h*h+1
constexpr size_t OFF_BLK = OFF_HD + (size_t)B * NPAD;  // blk_p
constexpr size_t OFF_D  = OFF_BLK + (size_t)B * NPAD;  // softmax denominators
constexpr size_t OFF_BIMG = OFF_D + (size_t)B * NPAD;  // block image, B*63*63 -> 8192
constexpr size_t OFF_ATT = OFF_BIMG + 8192;
constexpr size_t SZ_ATT = (size_t)B * NPAD * NPAD;     // 22,151,168 floats
constexpr size_t OFF_OUTA = OFF_ATT + SZ_ATT;          // atomic accumulation buffer
// total = OFF_OUTA + SZ_X ~ 97 MiB
constexpr int SPLITS = 8;
constexpr int MCHUNK = NPAD / SPLITS;  // 416
}
using namespace nl;

// ---------------- block detect (sobel + angle test) ----------------
__global__ __launch_bounds__(256) void nl_block(const float* __restrict__ x,
                                                const float* __restrict__ y,
                                                float* __restrict__ bimg) {
  int idx = blockIdx.x * 256 + threadIdx.x;
  if (idx >= B * H * W) return;
  int q = idx % W, t = idx / W;
  int p = t % H, b = t / H;
  float gx[3][3], gy[3][3];
#pragma unroll
  for (int dy = 0; dy < 3; ++dy)
#pragma unroll
    for (int dx = 0; dx < 3; ++dx) {
      int pp = p + dy - 1, qq = q + dx - 1;
      float vx = 0.f, vy = 0.f;
      if (pp >= 0 && pp < H && qq >= 0 && qq < W) {
        int base = (b * C * H + pp) * W + qq;
        vx = 0.299f * x[base] + 0.587f * x[base + H * W] + 0.114f * x[base + 2 * H * W];
        vy = 0.299f * y[base] + 0.587f * y[base + H * W] + 0.114f * y[base + 2 * H * W];
      }
      gx[dy][dx] = vx; gy[dy][dx] = vy;
    }
  float in_gx = (q == W - 1) ? 1.f : (-gx[0][0] + gx[0][2] - 2.f * gx[1][0] + 2.f * gx[1][2] - gx[2][0] + gx[2][2]);
  float in_gy = (p == H - 1) ? 1.f : (-gx[0][0] - 2.f * gx[0][1] - gx[0][2] + gx[2][0] + 2.f * gx[2][1] + gx[2][2]);
  float rf_gx = (q == W - 1) ? 1.f : (-gy[0][0] + gy[0][2] - 2.f * gy[1][0] + 2.f * gy[1][2] - gy[2][0] + gy[2][2]);
  float rf_gy = (p == H - 1) ? 1.f : (-gy[0][0] - 2.f * gy[0][1] - gy[0][2] + gy[2][0] + 2.f * gy[2][1] + gy[2][2]);
  float n_in = sqrtf(in_gx * in_gx + in_gy * in_gy);
  float n_rf = sqrtf(rf_gx * rf_gx + rf_gy * rf_gy);
  float cosv = (in_gx * rf_gx + in_gy * rf_gy + 0.001f) / (n_in * n_rf + 0.001f);
  float det = (n_in >= 29.f) ? ((n_rf >= 29.f) ? (1.f - cosv) : 1.f) : 0.f;
  bimg[(b * H + p) * W + q] = 1.f - det;
}

// ---------------- blk_p: 7x7 box mean of block image ----------------
__global__ __launch_bounds__(256) void nl_blkp(const float* __restrict__ bimg,
                                               float* __restrict__ blk) {
  int idx = blockIdx.x * 256 + threadIdx.x;
  if (idx >= B * NPAD) return;
  int n = idx % NPAD, b = idx / NPAD;
  float v = 0.f;
  if (n < N) {
    int i = n / NW, j = n % NW;
    float s = 0.f;
#pragma unroll
    for (int ky = 0; ky < K; ++ky)
#pragma unroll
      for (int kx = 0; kx < K; ++kx)
        s += bimg[(b * H + i + ky) * W + (j + kx)];
    v = s * (1.f / 49.f);
  }
  blk[idx] = v;
}

// ---------------- im2col for both images (zero-padded to [KSP][NPAD]) ----------------
__global__ __launch_bounds__(256) void nl_im2col(const float* __restrict__ x,
                                                 const float* __restrict__ y,
                                                 float* __restrict__ ws) {
  int idx = blockIdx.x * 256 + threadIdx.x;
  if (idx >= (int)(2 * SZ_X)) return;
  int n = idx % NPAD;
  int r1 = idx / NPAD;
  int k = r1 % KSP;
  int r2 = r1 / KSP;
  int b = r2 % B;
  int which = r2 / B;  // 0 -> Xr (from y), 1 -> Xi (from x)
  float v = 0.f;
  if (k < KS && n < N) {
    int c = k / 49, r = k % 49;
    int ky = r / 7, kx = r % 7;
    int i = n / NW, j = n % NW;
    const float* src = which ? x : y;
    v = src[((b * C + c) * H + (i + ky)) * W + (j + kx)];
  }
  ws[OFF_XR + idx] = v;
}

// ---------------- per-query sq = |patch|^2 and h-network ----------------
__global__ __launch_bounds__(256) void nl_sqh(const float* __restrict__ ws_xr,
                                              const float* __restrict__ w1,
                                              const float* __restrict__ b1,
                                              const float* __restrict__ w2,
                                              const float* __restrict__ b2,
                                              float* __restrict__ sq,
                                              float* __restrict__ hd) {
  int idx = blockIdx.x * 256 + threadIdx.x;
  if (idx >= B * NPAD) return;
  int n = idx % NPAD, b = idx / NPAD;
  if (n >= N) { sq[idx] = 0.f; hd[idx] = 1.f; return; }
  const float* Xr = ws_xr + (size_t)b * KSP * NPAD + n;
  float s = 0.f, h0 = b1[0], h1 = b1[1], h2 = b1[2];
  for (int k = 0; k < KS; ++k) {
    float v = Xr[(size_t)k * NPAD];
    s += v * v;
    h0 += v * w1[k];
    h1 += v * w1[KS + k];
    h2 += v * w1[2 * KS + k];
  }
  h0 = fmaxf(h0, 0.f); h1 = fmaxf(h1, 0.f); h2 = fmaxf(h2, 0.f);
  float h = h0 * w2[0] + h1 * w2[1] + h2 * w2[2] + b2[0];
  sq[idx] = s;
  hd[idx] = h * h + 1.f;
}

// ---------------- GEMM1: att = (2*Xr^T Xr - sq_n - sq_m) / hd_n ----------------
__global__ __launch_bounds__(256) void nl_gemm1(const float* __restrict__ ws_xr,
                                                const float* __restrict__ sq,
                                                const float* __restrict__ hd,
                                                float* __restrict__ att) {
  __shared__ float As[32][128];
  __shared__ float Bs[32][128];
  int b = blockIdx.z;
  const float* Xb = ws_xr + (size_t)b * KSP * NPAD;
  int row0 = blockIdx.y * 128, col0 = blockIdx.x * 128;
  int t = threadIdx.x;
  int tr = t >> 4, tc = t & 15;
  float acc[8][8];
#pragma unroll
  for (int i = 0; i < 8; ++i)
#pragma unroll
    for (int j = 0; j < 8; ++j) acc[i][j] = 0.f;

  for (int kt = 0; kt < KSP; kt += 32) {
#pragma unroll
    for (int u = 0; u < 4; ++u) {
      int e = t + u * 256;        // float4 id 0..1023
      int kk = e >> 5, cc = e & 31;
      float4 va = *(const float4*)(Xb + (size_t)(kt + kk) * NPAD + row0 + cc * 4);
      *(float4*)(&As[kk][cc * 4]) = va;
      float4 vb = *(const float4*)(Xb + (size_t)(kt + kk) * NPAD + col0 + cc * 4);
      *(float4*)(&Bs[kk][cc * 4]) = vb;
    }
    __syncthreads();
#pragma unroll
    for (int kk = 0; kk < 32; ++kk) {
      float a[8], bb[8];
      *(float4*)(&a[0]) = *(const float4*)(&As[kk][tr * 8]);
      *(float4*)(&a[4]) = *(const float4*)(&As[kk][tr * 8 + 4]);
      *(float4*)(&bb[0]) = *(const float4*)(&Bs[kk][tc * 8]);
      *(float4*)(&bb[4]) = *(const float4*)(&Bs[kk][tc * 8 + 4]);
#pragma unroll
      for (int i = 0; i < 8; ++i)
#pragma unroll
        for (int j = 0; j < 8; ++j) acc[i][j] = fmaf(a[i], bb[j], acc[i][j]);
    }
    __syncthreads();
  }
  float sqn[8], hdn[8], sqm[8];
#pragma unroll
  for (int i = 0; i < 8; ++i) {
    sqn[i] = sq[b * NPAD + row0 + tr * 8 + i];
    hdn[i] = hd[b * NPAD + row0 + tr * 8 + i];
  }
#pragma unroll
  for (int j = 0; j < 8; ++j) sqm[j] = sq[b * NPAD + col0 + tc * 8 + j];
  float* arow = att + ((size_t)b * NPAD + row0 + tr * 8) * NPAD + col0 + tc * 8;
#pragma unroll
  for (int i = 0; i < 8; ++i) {
    float v[8];
#pragma unroll
    for (int j = 0; j < 8; ++j)
      v[j] = (2.f * acc[i][j] - sqn[i] - sqm[j]) / hdn[i];
    *(float4*)(arow + (size_t)i * NPAD) = *(float4*)(&v[0]);
    *(float4*)(arow + (size_t)i * NPAD + 4) = *(float4*)(&v[4]);
  }
}

// ---------------- softmax rows: store e*blk, denominators to D ----------------
__global__ __launch_bounds__(256) void nl_softmax(float* __restrict__ att,
                                                  const float* __restrict__ blk,
                                                  float* __restrict__ Dv) {
  int n = blockIdx.x, b = blockIdx.y;
  int tid = threadIdx.x;
  float* row = att + ((size_t)b * NPAD + n) * NPAD;
  __shared__ float red[256];
  float lmax = -1e30f;
  for (int m = tid; m < N; m += 256) lmax = fmaxf(lmax, row[m]);
  red[tid] = lmax;
  __syncthreads();
  for (int s = 128; s > 0; s >>= 1) {
    if (tid < s) red[tid] = fmaxf(red[tid], red[tid + s]);
    __syncthreads();
  }
  float mx = red[0];
  __syncthreads();
  const float* bl = blk + b * NPAD;
  float s1 = 0.f, s2 = 0.f;
  for (int m = tid; m < N; m += 256) {
    float e = __expf(row[m] - mx);
    float eb = e * bl[m];
    row[m] = eb;
    s1 += e;
    s2 += eb;
  }
  for (int m = N + tid; m < NPAD; m += 256) row[m] = 0.f;  // zero pad cols
  red[tid] = s1;
  __syncthreads();
  for (int s = 128; s > 0; s >>= 1) {
    if (tid < s) red[tid] += red[tid + s];
    __syncthreads();
  }
  float s1t = red[0];
  __syncthreads();
  red[tid] = s2;
  __syncthreads();
  for (int s = 128; s > 0; s >>= 1) {
    if (tid < s) red[tid] += red[tid + s];
    __syncthreads();
  }
  if (tid == 0) Dv[b * NPAD + n] = red[0] + 0.001f * s1t;
}

// ---------------- GEMM2: out_p[k,n] = sum_m att[n,m]*Xi[k,m] / D[n], split-K=8 via atomics ----------------
__global__ __launch_bounds__(256) void nl_gemm2(const float* __restrict__ att,
                                                const float* __restrict__ ws_xi,
                                                const float* __restrict__ Dv,
                                                float* __restrict__ outp0) {
  __shared__ float Ps[32][65];    // [m][n] transposed in LDS
  __shared__ float Xs[32][161];   // [m][k]
  int b = blockIdx.z;
  int n0 = blockIdx.x * 64;
  int m0 = blockIdx.y * MCHUNK;   // 416 per split
  const float* attb = att + (size_t)b * NPAD * NPAD;
  const float* Xib = ws_xi + (size_t)b * KSP * NPAD;
  int t = threadIdx.x;
  int tn8 = t & 7;        // n = tn8 + 8*i
  int tk32 = t >> 3;      // k = tk32*5 + j
  float acc[8][5];
#pragma unroll
  for (int i = 0; i < 8; ++i)
#pragma unroll
    for (int j = 0; j < 5; ++j) acc[i][j] = 0.f;

  for (int mt = m0; mt < m0 + MCHUNK; mt += 32) {
#pragma unroll
    for (int u = 0; u < 2; ++u) {  // att tile 64x32
      int e = t + u * 256;
      int r = e >> 3, c4 = e & 7;
      float4 v = *(const float4*)(attb + (size_t)(n0 + r) * NPAD + mt + c4 * 4);
      Ps[c4 * 4 + 0][r] = v.x; Ps[c4 * 4 + 1][r] = v.y;
      Ps[c4 * 4 + 2][r] = v.z; Ps[c4 * 4 + 3][r] = v.w;
    }
#pragma unroll
    for (int u = 0; u < 5; ++u) {  // Xi tile 160x32
      int e = t + u * 256;
      int r = e >> 3, c4 = e & 7;
      float4 v = *(const float4*)(Xib + (size_t)r * NPAD + mt + c4 * 4);
      Xs[c4 * 4 + 0][r] = v.x; Xs[c4 * 4 + 1][r] = v.y;
      Xs[c4 * 4 + 2][r] = v.z; Xs[c4 * 4 + 3][r] = v.w;
    }
    __syncthreads();
#pragma unroll
    for (int mm = 0; mm < 32; ++mm) {
      float a[8], bb[5];
#pragma unroll
      for (int i = 0; i < 8; ++i) a[i] = Ps[mm][tn8 + 8 * i];
#pragma unroll
      for (int j = 0; j < 5; ++j) bb[j] = Xs[mm][tk32 * 5 + j];
#pragma unroll
      for (int i = 0; i < 8; ++i)
#pragma unroll
        for (int j = 0; j < 5; ++j) acc[i][j] = fmaf(a[i], bb[j], acc[i][j]);
    }
    __syncthreads();
  }
  float* outp = outp0 + (size_t)b * KSP * NPAD;
#pragma unroll
  for (int i = 0; i < 8; ++i) {
    int n = n0 + tn8 + 8 * i;
    if (n < N) {
      float dinv = 1.0f / Dv[b * NPAD + n];
#pragma unroll
      for (int j = 0; j < 5; ++j) {
        int k = tk32 * 5 + j;
        atomicAdd(outp + (size_t)k * NPAD + n, acc[i][j] * dinv);
      }
    }
  }
}

// ---------------- fold (overlap-add adjoint of im2col) + weight divide ----------------
__global__ __launch_bounds__(256) void nl_fold(const float* __restrict__ outA,
                                               float* __restrict__ out) {
  int idx = blockIdx.x * 256 + threadIdx.x;
  if (idx >= B * C * H * W) return;
  int q = idx % W, t = idx / W;
  int p = t % H, t2 = t / H;
  int c = t2 % C, b = t2 / C;
  float s = 0.f;
#pragma unroll
  for (int ky = 0; ky < K; ++ky) {
    int iy = p - ky;
    if (iy < 0 || iy >= NH) continue;
#pragma unroll
    for (int kx = 0; kx < K; ++kx) {
      int jx = q - kx;
      if (jx < 0 || jx >= NW) continue;
      size_t o = ((size_t)(b * KSP + c * 49 + ky * 7 + kx)) * NPAD + iy * NW + jx;
      s += outA[o];
    }
  }
  int cy = min(p, 6) - max(0, p - 56) + 1;
  int cx = min(q, 6) - max(0, q - 56) + 1;
  out[idx] = s / (float)(cy * cx);
}

extern "C" void kernel_launch(void* const* d_in, const int* in_sizes, int n_in,
                              void* d_out, int out_size, void* d_ws, size_t ws_size,
                              hipStream_t stream) {
  const float* x = (const float*)d_in[0];
  const float* y = (const float*)d_in[1];
  const float* w1 = (const float*)d_in[2];
  const float* b1 = (const float*)d_in[3];
  const float* w2 = (const float*)d_in[4];
  const float* b2 = (const float*)d_in[5];
  float* ws = (float*)d_ws;
  float* out = (float*)d_out;

  float* Xr = ws + OFF_XR;
  float* Xi = ws + OFF_XI;
  float* sq = ws + OFF_SQ;
  float* hd = ws + OFF_HD;
  float* blk = ws + OFF_BLK;
  float* Dv = ws + OFF_D;
  float* bimg = ws + OFF_BIMG;
  float* att = ws + OFF_ATT;
  float* outA = ws + OFF_OUTA;

  // zero the atomic-accumulation buffer (graph-capture-safe async memset)
  hipMemsetAsync(outA, 0, SZ_X * sizeof(float), stream);

  nl_block<<<(B * H * W + 255) / 256, 256, 0, stream>>>(x, y, bimg);
  nl_im2col<<<(int)((2 * SZ_X + 255) / 256), 256, 0, stream>>>(x, y, ws);
  nl_blkp<<<(B * NPAD + 255) / 256, 256, 0, stream>>>(bimg, blk);
  nl_sqh<<<(B * NPAD + 255) / 256, 256, 0, stream>>>(Xr, w1, b1, w2, b2, sq, hd);
  nl_gemm1<<<dim3(NPAD / 128, NPAD / 128, B), 256, 0, stream>>>(Xr, sq, hd, att);
  nl_softmax<<<dim3(N, B), 256, 0, stream>>>(att, blk, Dv);
  nl_gemm2<<<dim3(NPAD / 64, SPLITS, B), 256, 0, stream>>>(att, Xi, Dv, outA);
  nl_fold<<<(B * C * H * W + 255) / 256, 256, 0, stream>>>(outA, out);
}